// Round 10
// baseline (187.403 us; speedup 1.0000x reference)
//
#include <hip/hip_runtime.h>

// Shape: N=300000 src nodes, K=6 neighbors, F=64 features, N_up=75000 selections.
// Three dispatches. Harness overhead (ws 0xAA re-poison = 307MB fill @ ~47us +
// input restore) is a fixed ~65-70us floor inside the timed region (round-8
// profile: fillBufferAligned tops the table) — only mark/build/gather are ours.
//   mark   : cnt[sel[u]] = 0. No memset — 0xAAAAAAAA poison is already a
//            negative sentinel (validated round 7).
//   build  : 8 edges/thread (2x int4 + 2x float4 coalesced), 8 independent
//            plain cnt pre-checks (kills 78% of atomics), up to 8 independent
//            atomicAdd+store chains in flight (atomic-MLP was the bottleneck).
//   gather : quarter-wave float4, 8 dests/wave — 16 independent 1KB feature
//            loads in flight; nontemporal output stores (d_out never re-read)
//            via native ext_vector_type (HIP float4 class rejected by builtin).
// CAP=32: 256B-aligned rows; P(in-degree>=32 | ~Poisson(6)) < 1e-13.

#define KNB 6
#define FDIM 64
#define CAP 32
#define EB 8

typedef float nfloat4 __attribute__((ext_vector_type(4)));

__global__ void mark_kernel(const int* __restrict__ sel,
                            int* __restrict__ cnt,
                            int Nup) {
    const int u = blockIdx.x * blockDim.x + threadIdx.x;
    if (u < Nup) cnt[sel[u]] = 0;
}

__global__ __launch_bounds__(256)
void build_kernel(const float* __restrict__ weight,
                  const float* __restrict__ nweights,
                  const int*   __restrict__ nidx,
                  int* __restrict__ cnt,
                  int2* __restrict__ table,
                  int E) {
    const int t  = blockIdx.x * blockDim.x + threadIdx.x;
    const int e0 = t * EB;
    if (e0 >= E) return;

    // E = 1.8M divisible by 8; e0*4B is 32B-aligned.
    const int4   ia = *(const int4*)(nidx + e0);
    const int4   ib = *(const int4*)(nidx + e0 + 4);
    const float4 na = *(const float4*)(nweights + e0);
    const float4 nb = *(const float4*)(nweights + e0 + 4);
    const int   idx[EB] = {ia.x, ia.y, ia.z, ia.w, ib.x, ib.y, ib.z, ib.w};
    const float nw [EB] = {na.x, na.y, na.z, na.w, nb.x, nb.y, nb.z, nb.w};

    // 8 independent pre-check reads — all issue before any is consumed.
    int c[EB];
    #pragma unroll
    for (int j = 0; j < EB; ++j)
        c[j] = (idx[j] >= 0) ? cnt[idx[j]] : -1;

    #pragma unroll
    for (int j = 0; j < EB; ++j) {
        if (c[j] >= 0) {  // marked dest (cnt monotone non-negative iff marked)
            const int slot = atomicAdd(&cnt[idx[j]], 1);
            if (slot < CAP) {
                const int e = e0 + j;
                const int i = e / KNB;
                float w = weight[i];
                w = w > 0.0f ? w : 0.0f;
                table[(size_t)idx[j] * CAP + slot] =
                    make_int2(i, __float_as_int(nw[j] * w));
            }
        }
    }
}

// Quarter-wave gather, 8 destinations per wave:
//   lane = 16*q + l ; quarter q handles dests u0+q and u0+4+q; lane chunk l
//   covers bytes [16l,16l+16) of the 256B feature row.
__global__ __launch_bounds__(256)
void gather_kernel(const float* __restrict__ features,
                   const int*   __restrict__ sel,
                   const int*   __restrict__ cnt,
                   const int2*  __restrict__ table,
                   float* __restrict__ out,
                   int Nup) {
    const int wave = blockIdx.x * (blockDim.x >> 6) + (threadIdx.x >> 6);
    const int lane = threadIdx.x & 63;
    const int q    = lane >> 4;
    const int l    = lane & 15;
    const int u0   = wave * 8;
    if (u0 >= Nup) return;

    const float4* feat4 = (const float4*)features;

    const int uA = u0 + q;
    const int uB = u0 + 4 + q;
    const int uAc = (uA < Nup) ? uA : (Nup - 1);
    const int uBc = (uB < Nup) ? uB : (Nup - 1);

    // Level 1: sel (2 independent, coalesced/broadcast)
    const int sA = sel[uAc];
    const int sB = sel[uBc];
    // Level 2: cnt + table rows (10 independent loads)
    int cA = cnt[sA], cB = cnt[sB];
    const int4* rowA = (const int4*)(table + (size_t)sA * CAP);
    const int4* rowB = (const int4*)(table + (size_t)sB * CAP);
    int4 tA[4], tB[4];
    #pragma unroll
    for (int p = 0; p < 4; ++p) { tA[p] = rowA[p]; tB[p] = rowB[p]; }

    cA = cA < 0 ? 0 : (cA > CAP ? CAP : cA);
    cB = cB < 0 ? 0 : (cB > CAP ? CAP : cB);

    int   srcA[8], srcB[8];
    float wnA[8],  wnB[8];
    #pragma unroll
    for (int p = 0; p < 4; ++p) {
        srcA[2*p]   = tA[p].x; wnA[2*p]   = __int_as_float(tA[p].y);
        srcA[2*p+1] = tA[p].z; wnA[2*p+1] = __int_as_float(tA[p].w);
        srcB[2*p]   = tB[p].x; wnB[2*p]   = __int_as_float(tB[p].y);
        srcB[2*p+1] = tB[p].z; wnB[2*p+1] = __int_as_float(tB[p].w);
    }
    #pragma unroll
    for (int j = 0; j < 8; ++j) {  // predicate-safe clamp (row 0 stays cached)
        const bool vA = j < cA, vB = j < cB;
        srcA[j] = vA ? srcA[j] : 0;  wnA[j] = vA ? wnA[j] : 0.0f;
        srcB[j] = vB ? srcB[j] : 0;  wnB[j] = vB ? wnB[j] : 0.0f;
    }

    // Level 3: 16 independent float4 loads (each instruction = 4 rows, 1KB)
    float4 fA[8], fB[8];
    #pragma unroll
    for (int j = 0; j < 8; ++j) fA[j] = feat4[(size_t)srcA[j] * 16 + l];
    #pragma unroll
    for (int j = 0; j < 8; ++j) fB[j] = feat4[(size_t)srcB[j] * 16 + l];

    float4 aA = make_float4(0.f,0.f,0.f,0.f), aB = make_float4(0.f,0.f,0.f,0.f);
    float dA = 0.f, dB = 0.f;
    #pragma unroll
    for (int j = 0; j < 8; ++j) {
        aA.x = fmaf(wnA[j], fA[j].x, aA.x); aA.y = fmaf(wnA[j], fA[j].y, aA.y);
        aA.z = fmaf(wnA[j], fA[j].z, aA.z); aA.w = fmaf(wnA[j], fA[j].w, aA.w);
        dA += wnA[j];
        aB.x = fmaf(wnB[j], fB[j].x, aB.x); aB.y = fmaf(wnB[j], fB[j].y, aB.y);
        aB.z = fmaf(wnB[j], fB[j].z, aB.z); aB.w = fmaf(wnB[j], fB[j].w, aB.w);
        dB += wnB[j];
    }
    // Rare tails (in-degree > 8, ~15% of rows; >16 ~0.1%).
    for (int j = 8; j < cA; ++j) {
        const int2 tt = table[(size_t)sA * CAP + j];
        const float wn = __int_as_float(tt.y);
        const float4 fx = feat4[(size_t)tt.x * 16 + l];
        aA.x = fmaf(wn, fx.x, aA.x); aA.y = fmaf(wn, fx.y, aA.y);
        aA.z = fmaf(wn, fx.z, aA.z); aA.w = fmaf(wn, fx.w, aA.w);
        dA += wn;
    }
    for (int j = 8; j < cB; ++j) {
        const int2 tt = table[(size_t)sB * CAP + j];
        const float wn = __int_as_float(tt.y);
        const float4 fx = feat4[(size_t)tt.x * 16 + l];
        aB.x = fmaf(wn, fx.x, aB.x); aB.y = fmaf(wn, fx.y, aB.y);
        aB.z = fmaf(wn, fx.z, aB.z); aB.w = fmaf(wn, fx.w, aB.w);
        dB += wn;
    }

    // Nontemporal stores (native vector type — HIP float4 class rejected).
    nfloat4* out4 = (nfloat4*)out;
    if (uA < Nup) {
        const float d = dA + 0.001f;  // dsum>=0 so d>=0.001 (matches ref)
        nfloat4 v; v.x = aA.x/d; v.y = aA.y/d; v.z = aA.z/d; v.w = aA.w/d;
        __builtin_nontemporal_store(v, out4 + (size_t)uA * 16 + l);
    }
    if (uB < Nup) {
        const float d = dB + 0.001f;
        nfloat4 v; v.x = aB.x/d; v.y = aB.y/d; v.z = aB.z/d; v.w = aB.w/d;
        __builtin_nontemporal_store(v, out4 + (size_t)uB * 16 + l);
    }
}

extern "C" void kernel_launch(void* const* d_in, const int* in_sizes, int n_in,
                              void* d_out, int out_size, void* d_ws, size_t ws_size,
                              hipStream_t stream) {
    const float* features = (const float*)d_in[0];  // N*64
    const float* weight   = (const float*)d_in[1];  // N
    const float* nweights = (const float*)d_in[2];  // N*6
    const int*   nidx     = (const int*)d_in[3];    // N*6
    const int*   sel      = (const int*)d_in[4];    // N_up

    const int N   = in_sizes[1];
    const int Nup = in_sizes[4];
    const int E   = N * KNB;

    // ws layout: cnt[N] | table[N*CAP] (int2) -> 1.2 MB + 76.8 MB
    int*  cnt   = (int*)d_ws;
    int2* table = (int2*)(cnt + N);

    const int T = 256;
    mark_kernel<<<(Nup + T - 1) / T, T, 0, stream>>>(sel, cnt, Nup);

    const int nthreads_build = E / EB;
    build_kernel<<<(nthreads_build + T - 1) / T, T, 0, stream>>>(
        weight, nweights, nidx, cnt, table, E);

    const int waves  = (Nup + 7) / 8;
    const int wpb    = T / 64;                 // 4 waves per block
    const int blocks = (waves + wpb - 1) / wpb;
    gather_kernel<<<blocks, T, 0, stream>>>(features, sel, cnt, table,
                                            (float*)d_out, Nup);
}

// Round 11
// 178.782 us; speedup vs baseline: 1.0482x; 1.0482x over previous
//
#include <hip/hip_runtime.h>

// Shape: N=300000 src nodes, K=6 neighbors, F=64 features, N_up=75000 selections.
// Harness re-poison (2x 307MB fill @ ~47us) is a fixed floor; ours is mark/build/gather.
//   mark   : cnt[sel[u]] = 0 AND set bit in a 37.5KB read-only bitmap.
//            cnt needs no memset (0xAA poison is a negative sentinel, r7).
//   build  : 4 edges/thread (int4/float4 coalesced). Pre-check via the BITMAP
//            (L1-resident, never invalidated — the old cnt pre-check shared
//            cache lines with the atomics and ping-ponged across XCD L2s,
//            round-10 post-mortem). Only ~22% of edges touch the atomic lines.
//   gather : quarter-wave float4, 8 dests/wave — 16 independent 1KB feature
//            loads in flight; nontemporal output stores.
// CAP=32: 256B-aligned rows; P(in-degree>=32 | ~Poisson(6)) < 1e-13.

#define KNB 6
#define FDIM 64
#define CAP 32
#define EB 4

typedef float nfloat4 __attribute__((ext_vector_type(4)));

__global__ void mark_kernel(const int* __restrict__ sel,
                            int* __restrict__ cnt,
                            unsigned int* __restrict__ bitmap,
                            int Nup) {
    const int u = blockIdx.x * blockDim.x + threadIdx.x;
    if (u < Nup) {
        const int s = sel[u];
        cnt[s] = 0;
        atomicOr(&bitmap[s >> 5], 1u << (s & 31));
    }
}

__global__ __launch_bounds__(256)
void build_kernel(const float* __restrict__ weight,
                  const float* __restrict__ nweights,
                  const int*   __restrict__ nidx,
                  const unsigned int* __restrict__ bitmap,
                  int* __restrict__ cnt,
                  int2* __restrict__ table,
                  int E) {
    const int t  = blockIdx.x * blockDim.x + threadIdx.x;
    const int e0 = t * EB;
    if (e0 >= E) return;

    // E = 1.8M divisible by 4; e0*4B is 16B-aligned.
    const int4   i4 = *(const int4*)(nidx + e0);
    const float4 n4 = *(const float4*)(nweights + e0);
    const int   idx[EB] = {i4.x, i4.y, i4.z, i4.w};
    const float nw [EB] = {n4.x, n4.y, n4.z, n4.w};

    // Pre-check against the read-only bitmap: L1 hits, no coherence traffic.
    bool sel_f[EB];
    #pragma unroll
    for (int j = 0; j < EB; ++j) {
        const int id = idx[j];
        sel_f[j] = (id >= 0) && ((bitmap[id >> 5] >> (id & 31)) & 1u);
    }

    #pragma unroll
    for (int j = 0; j < EB; ++j) {
        if (sel_f[j]) {
            const int slot = atomicAdd(&cnt[idx[j]], 1);
            if ((unsigned)slot < CAP) {   // also guards stray/negative slots
                const int e = e0 + j;
                const int i = e / KNB;
                float w = weight[i];
                w = w > 0.0f ? w : 0.0f;
                table[(size_t)idx[j] * CAP + slot] =
                    make_int2(i, __float_as_int(nw[j] * w));
            }
        }
    }
}

// Quarter-wave gather, 8 destinations per wave:
//   lane = 16*q + l ; quarter q handles dests u0+q and u0+4+q; lane chunk l
//   covers bytes [16l,16l+16) of the 256B feature row.
__global__ __launch_bounds__(256)
void gather_kernel(const float* __restrict__ features,
                   const int*   __restrict__ sel,
                   const int*   __restrict__ cnt,
                   const int2*  __restrict__ table,
                   float* __restrict__ out,
                   int Nup) {
    const int wave = blockIdx.x * (blockDim.x >> 6) + (threadIdx.x >> 6);
    const int lane = threadIdx.x & 63;
    const int q    = lane >> 4;
    const int l    = lane & 15;
    const int u0   = wave * 8;
    if (u0 >= Nup) return;

    const float4* feat4 = (const float4*)features;

    const int uA = u0 + q;
    const int uB = u0 + 4 + q;
    const int uAc = (uA < Nup) ? uA : (Nup - 1);
    const int uBc = (uB < Nup) ? uB : (Nup - 1);

    const int sA = sel[uAc];
    const int sB = sel[uBc];
    int cA = cnt[sA], cB = cnt[sB];
    const int4* rowA = (const int4*)(table + (size_t)sA * CAP);
    const int4* rowB = (const int4*)(table + (size_t)sB * CAP);
    int4 tA[4], tB[4];
    #pragma unroll
    for (int p = 0; p < 4; ++p) { tA[p] = rowA[p]; tB[p] = rowB[p]; }

    cA = cA < 0 ? 0 : (cA > CAP ? CAP : cA);
    cB = cB < 0 ? 0 : (cB > CAP ? CAP : cB);

    int   srcA[8], srcB[8];
    float wnA[8],  wnB[8];
    #pragma unroll
    for (int p = 0; p < 4; ++p) {
        srcA[2*p]   = tA[p].x; wnA[2*p]   = __int_as_float(tA[p].y);
        srcA[2*p+1] = tA[p].z; wnA[2*p+1] = __int_as_float(tA[p].w);
        srcB[2*p]   = tB[p].x; wnB[2*p]   = __int_as_float(tB[p].y);
        srcB[2*p+1] = tB[p].z; wnB[2*p+1] = __int_as_float(tB[p].w);
    }
    #pragma unroll
    for (int j = 0; j < 8; ++j) {  // predicate-safe clamp (row 0 stays cached)
        const bool vA = j < cA, vB = j < cB;
        srcA[j] = vA ? srcA[j] : 0;  wnA[j] = vA ? wnA[j] : 0.0f;
        srcB[j] = vB ? srcB[j] : 0;  wnB[j] = vB ? wnB[j] : 0.0f;
    }

    // 16 independent float4 loads (each instruction = 4 rows, 1KB)
    float4 fA[8], fB[8];
    #pragma unroll
    for (int j = 0; j < 8; ++j) fA[j] = feat4[(size_t)srcA[j] * 16 + l];
    #pragma unroll
    for (int j = 0; j < 8; ++j) fB[j] = feat4[(size_t)srcB[j] * 16 + l];

    float4 aA = make_float4(0.f,0.f,0.f,0.f), aB = make_float4(0.f,0.f,0.f,0.f);
    float dA = 0.f, dB = 0.f;
    #pragma unroll
    for (int j = 0; j < 8; ++j) {
        aA.x = fmaf(wnA[j], fA[j].x, aA.x); aA.y = fmaf(wnA[j], fA[j].y, aA.y);
        aA.z = fmaf(wnA[j], fA[j].z, aA.z); aA.w = fmaf(wnA[j], fA[j].w, aA.w);
        dA += wnA[j];
        aB.x = fmaf(wnB[j], fB[j].x, aB.x); aB.y = fmaf(wnB[j], fB[j].y, aB.y);
        aB.z = fmaf(wnB[j], fB[j].z, aB.z); aB.w = fmaf(wnB[j], fB[j].w, aB.w);
        dB += wnB[j];
    }
    // Rare tails (in-degree > 8, ~15% of rows; >16 ~0.1%).
    for (int j = 8; j < cA; ++j) {
        const int2 tt = table[(size_t)sA * CAP + j];
        const float wn = __int_as_float(tt.y);
        const float4 fx = feat4[(size_t)tt.x * 16 + l];
        aA.x = fmaf(wn, fx.x, aA.x); aA.y = fmaf(wn, fx.y, aA.y);
        aA.z = fmaf(wn, fx.z, aA.z); aA.w = fmaf(wn, fx.w, aA.w);
        dA += wn;
    }
    for (int j = 8; j < cB; ++j) {
        const int2 tt = table[(size_t)sB * CAP + j];
        const float wn = __int_as_float(tt.y);
        const float4 fx = feat4[(size_t)tt.x * 16 + l];
        aB.x = fmaf(wn, fx.x, aB.x); aB.y = fmaf(wn, fx.y, aB.y);
        aB.z = fmaf(wn, fx.z, aB.z); aB.w = fmaf(wn, fx.w, aB.w);
        dB += wn;
    }

    // Nontemporal stores: d_out is never re-read.
    nfloat4* out4 = (nfloat4*)out;
    if (uA < Nup) {
        const float d = dA + 0.001f;  // dsum>=0 so d>=0.001 (matches ref)
        nfloat4 v; v.x = aA.x/d; v.y = aA.y/d; v.z = aA.z/d; v.w = aA.w/d;
        __builtin_nontemporal_store(v, out4 + (size_t)uA * 16 + l);
    }
    if (uB < Nup) {
        const float d = dB + 0.001f;
        nfloat4 v; v.x = aB.x/d; v.y = aB.y/d; v.z = aB.z/d; v.w = aB.w/d;
        __builtin_nontemporal_store(v, out4 + (size_t)uB * 16 + l);
    }
}

extern "C" void kernel_launch(void* const* d_in, const int* in_sizes, int n_in,
                              void* d_out, int out_size, void* d_ws, size_t ws_size,
                              hipStream_t stream) {
    const float* features = (const float*)d_in[0];  // N*64
    const float* weight   = (const float*)d_in[1];  // N
    const float* nweights = (const float*)d_in[2];  // N*6
    const int*   nidx     = (const int*)d_in[3];    // N*6
    const int*   sel      = (const int*)d_in[4];    // N_up

    const int N   = in_sizes[1];
    const int Nup = in_sizes[4];
    const int E   = N * KNB;
    const int nbm = (N + 31) / 32;   // bitmap words

    // ws layout: cnt[N] | bitmap[nbm] | pad to 64B | table[N*CAP] (int2)
    int* cnt             = (int*)d_ws;
    unsigned int* bitmap = (unsigned int*)(cnt + N);
    size_t table_off     = ((size_t)(N + nbm) * 4 + 255) & ~(size_t)255;
    int2* table          = (int2*)((char*)d_ws + table_off);

    // Bitmap must start clean (poison bits would fake-flag dests). 37.5KB.
    hipMemsetAsync(bitmap, 0, (size_t)nbm * sizeof(unsigned int), stream);

    const int T = 256;
    mark_kernel<<<(Nup + T - 1) / T, T, 0, stream>>>(sel, cnt, bitmap, Nup);

    const int nthreads_build = E / EB;
    build_kernel<<<(nthreads_build + T - 1) / T, T, 0, stream>>>(
        weight, nweights, nidx, bitmap, cnt, table, E);

    const int waves  = (Nup + 7) / 8;
    const int wpb    = T / 64;                 // 4 waves per block
    const int blocks = (waves + wpb - 1) / wpb;
    gather_kernel<<<blocks, T, 0, stream>>>(features, sel, cnt, table,
                                            (float*)d_out, Nup);
}